// Round 1
// baseline (1264.735 us; speedup 1.0000x reference)
//
#include <hip/hip_runtime.h>
#include <math.h>

#define TSEQ 256
#define CEMB 384
#define QKV_LD 1152

typedef short short8 __attribute__((ext_vector_type(8)));
typedef float f32x4 __attribute__((ext_vector_type(4)));

// fp32 -> bf16 bits, round-to-nearest-even (finite values only).
static __device__ __forceinline__ short f2bf(float f) {
    union { float f; unsigned u; } a;
    a.f = f;
    unsigned u = a.u + 0x7fffu + ((a.u >> 16) & 1u);
    return (short)(u >> 16);
}

// global -> LDS direct DMA, 16 bytes per lane. LDS dest must be the
// wave-uniform base; HW adds lane*16. Global address is per-lane.
static __device__ __forceinline__ void gload_lds16(const unsigned short* g,
                                                   unsigned short* l) {
    __builtin_amdgcn_global_load_lds(
        (const __attribute__((address_space(1))) unsigned int*)g,
        (__attribute__((address_space(3))) unsigned int*)l, 16, 0, 0);
}

// ---------------------------------------------------------------------------
// cast x (fp32) -> bf16, vectorized 8-wide
// ---------------------------------------------------------------------------
__global__ __launch_bounds__(256) void cast_x_kernel(
    const float* __restrict__ x, unsigned short* __restrict__ xb, int n8)
{
    int i = blockIdx.x * 256 + threadIdx.x;
    const int stride = gridDim.x * 256;
    for (; i < n8; i += stride) {
        const float* s = x + (size_t)i * 8;
        float4 a = *(const float4*)(s);
        float4 c = *(const float4*)(s + 4);
        short8 o;
        o[0] = f2bf(a.x); o[1] = f2bf(a.y); o[2] = f2bf(a.z); o[3] = f2bf(a.w);
        o[4] = f2bf(c.x); o[5] = f2bf(c.y); o[6] = f2bf(c.z); o[7] = f2bf(c.w);
        *(short8*)(xb + (size_t)i * 8) = o;
    }
}

// ---------------------------------------------------------------------------
// cast + transpose weights: Wt[n*K + k] = bf16(W[k*N + n]).  Tiny, once.
// ---------------------------------------------------------------------------
__global__ __launch_bounds__(256) void cast_wt_kernel(
    const float* __restrict__ W, unsigned short* __restrict__ Wt, int K, int N)
{
    int i = blockIdx.x * 256 + threadIdx.x;
    if (i < K * N) {
        int n = i / K;
        int k = i - n * K;
        Wt[i] = (unsigned short)f2bf(W[(size_t)k * N + n]);
    }
}

// ---------------------------------------------------------------------------
// bf16 MFMA GEMM (B pre-transposed): C[m,n] = sum_k A[m,k]*Bt[n,k] + bias[n]
// A [M][K] bf16, Bt [N][K] bf16, C bf16 or fp32 [M][N].
// 128x128 tile, BK=32, 4 waves each computing a 64x64 sub-tile (4x4 frags of
// 16x16x32). global_load_lds width-16 staging, linear [128][32] LDS.
// Layouts (m89/m97-verified): A-frag lane: A[l16][quad*8+j]; B-frag lane:
// B[quad*8+j][l16]; D: row=quad*4+r, col=l16.
// ---------------------------------------------------------------------------
template <int OUT_BF16>
__global__ __launch_bounds__(256) void gemm_bf16_kernel(
    const unsigned short* __restrict__ A, const unsigned short* __restrict__ Bt,
    const float* __restrict__ bias, void* __restrict__ Cout,
    int M, int N, int K)
{
    __shared__ unsigned short As[128 * 32];
    __shared__ unsigned short Bs[128 * 32];

    const int tid  = threadIdx.x;
    const int wave = tid >> 6;
    const int lane = tid & 63;
    const int quad = lane >> 4;
    const int l16  = lane & 15;
    const int wr   = wave >> 1;       // wave row 0..1
    const int wc   = wave & 1;        // wave col 0..1

    const int n0 = blockIdx.x * 128;
    const int m0 = blockIdx.y * 128;

    // staging: chunk c = tid covers LDS row c>>2, cols (c&3)*8..+8 (16B);
    // chunk c+256 covers row +64.
    const int srow = tid >> 2;
    const int scol = (tid & 3) * 8;
    const unsigned short* Abase = A  + (size_t)(m0 + srow) * K + scol;
    const unsigned short* Bbase = Bt + (size_t)(n0 + srow) * K + scol;
    unsigned short* As_w0 = As + (wave << 9);          // wave*512 shorts
    unsigned short* As_w1 = As + 2048 + (wave << 9);
    unsigned short* Bs_w0 = Bs + (wave << 9);
    unsigned short* Bs_w1 = Bs + 2048 + (wave << 9);

    f32x4 acc[4][4];
    #pragma unroll
    for (int mi = 0; mi < 4; ++mi)
        #pragma unroll
        for (int ni = 0; ni < 4; ++ni) acc[mi][ni] = (f32x4){0.f, 0.f, 0.f, 0.f};

    for (int kk = 0; kk < K; kk += 32) {
        gload_lds16(Abase + kk, As_w0);
        gload_lds16(Abase + (size_t)64 * K + kk, As_w1);
        gload_lds16(Bbase + kk, Bs_w0);
        gload_lds16(Bbase + (size_t)64 * K + kk, Bs_w1);
        __syncthreads();   // drains vmcnt -> staged data visible

        short8 af[4], bfr[4];
        #pragma unroll
        for (int mi = 0; mi < 4; ++mi)
            af[mi] = *(const short8*)&As[(wr * 64 + mi * 16 + l16) * 32 + quad * 8];
        #pragma unroll
        for (int ni = 0; ni < 4; ++ni)
            bfr[ni] = *(const short8*)&Bs[(wc * 64 + ni * 16 + l16) * 32 + quad * 8];

        #pragma unroll
        for (int mi = 0; mi < 4; ++mi)
            #pragma unroll
            for (int ni = 0; ni < 4; ++ni)
                acc[mi][ni] = __builtin_amdgcn_mfma_f32_16x16x32_bf16(
                    af[mi], bfr[ni], acc[mi][ni], 0, 0, 0);

        __syncthreads();   // all waves done reading before next overwrite
    }

    #pragma unroll
    for (int ni = 0; ni < 4; ++ni) {
        const int n = n0 + wc * 64 + ni * 16 + l16;
        const float bv = bias[n];
        #pragma unroll
        for (int mi = 0; mi < 4; ++mi) {
            #pragma unroll
            for (int r = 0; r < 4; ++r) {
                const int m = m0 + wr * 64 + mi * 16 + quad * 4 + r;
                float v = acc[mi][ni][r] + bv;
                if (OUT_BF16)
                    ((unsigned short*)Cout)[(size_t)m * N + n] = (unsigned short)f2bf(v);
                else
                    ((float*)Cout)[(size_t)m * N + n] = v;
            }
        }
    }
}

// ---------------------------------------------------------------------------
// V transpose: Vt[b][c][t] = QKVb[b*T + t][2C + c]   (bf16 -> bf16)
// ---------------------------------------------------------------------------
__global__ __launch_bounds__(256) void transpose_v_kernel(
    const unsigned short* __restrict__ QKVb, unsigned short* __restrict__ Vt)
{
    const int b  = blockIdx.y;
    const int t0 = blockIdx.x * 32;
    const int tid = threadIdx.x;
    for (int i = tid; i < 1536; i += 256) {
        int c  = i % 384;
        int tg = (i / 384) * 8;
        const unsigned short* src =
            QKVb + ((size_t)b * TSEQ + t0 + tg) * QKV_LD + 2 * CEMB + c;
        short8 o;
        #pragma unroll
        for (int j = 0; j < 8; ++j) o[j] = (short)src[(size_t)j * QKV_LD];
        *(short8*)(Vt + ((size_t)b * CEMB + c) * TSEQ + t0 + tg) = o;
    }
}

// ---------------------------------------------------------------------------
// Flash attention, bf16 MFMA 16x16x32. One wave = one 16-row Q strip.
// Q/K read bf16 from QKVb (ld=1152); V from Vt (transposed). Output bf16
// row-major into Ob [Mc][384] for the proj GEMM.
// ---------------------------------------------------------------------------
__global__ __launch_bounds__(256, 2) void attn_mfma_kernel(
    const unsigned short* __restrict__ QKVb, const unsigned short* __restrict__ Vt,
    unsigned short* __restrict__ Ob, int swizzle)
{
    int bid = blockIdx.x;
    int b, g;
    if (swizzle) {   // keep one batch's 4 blocks on one XCD (round-robin assumption)
        g = (bid >> 3) & 3;
        b = ((bid >> 5) << 3) | (bid & 7);
    } else {
        b = bid >> 2;
        g = bid & 3;
    }
    const int wave = threadIdx.x >> 6;
    const int lane = threadIdx.x & 63;
    const int quad = lane >> 4;
    const int l16  = lane & 15;
    const int Q0   = g * 64 + wave * 16;   // this wave's first q row

    __shared__ unsigned short Pbuf[4][16 * 32];
    unsigned short* Pw = &Pbuf[wave][0];

    const float scale = 0.051031036307982884f;  // 1/sqrt(384)

    // ---- load Q fragments (A-operand), already bf16 ----
    const unsigned short* qbase = QKVb + ((size_t)b * TSEQ + Q0) * QKV_LD;
    short8 qf[12];
    #pragma unroll
    for (int f = 0; f < 12; ++f)
        qf[f] = *(const short8*)(qbase + (size_t)l16 * QKV_LD + f * 32 + quad * 8);

    f32x4 acc[24];
    #pragma unroll
    for (int ct = 0; ct < 24; ++ct) acc[ct] = (f32x4){0.f, 0.f, 0.f, 0.f};
    float m_run[4] = {-1e30f, -1e30f, -1e30f, -1e30f};
    float l_run[4] = {0.f, 0.f, 0.f, 0.f};

    const unsigned short* kB = QKVb + (size_t)b * TSEQ * QKV_LD + CEMB;
    const unsigned short* vB = Vt + (size_t)b * CEMB * TSEQ;

    const int nkt = (Q0 + 16 + 31) >> 5;   // k-tiles of 32 covering k <= Q0+15

    for (int kt = 0; kt < nkt; ++kt) {
        const int k0 = kt * 32;

        // ---- S strip: two 16x16 halves, K accumulated over 12 frags ----
        f32x4 s0 = (f32x4){0.f, 0.f, 0.f, 0.f};
        f32x4 s1 = (f32x4){0.f, 0.f, 0.f, 0.f};
        const unsigned short* kp0 = kB + (size_t)(k0 + l16) * QKV_LD + quad * 8;
        const unsigned short* kp1 = kp0 + (size_t)16 * QKV_LD;
        #pragma unroll
        for (int f = 0; f < 12; ++f) {
            short8 b0 = *(const short8*)(kp0 + f * 32);
            short8 b1 = *(const short8*)(kp1 + f * 32);
            s0 = __builtin_amdgcn_mfma_f32_16x16x32_bf16(qf[f], b0, s0, 0, 0, 0);
            s1 = __builtin_amdgcn_mfma_f32_16x16x32_bf16(qf[f], b1, s1, 0, 0, 0);
        }

        // ---- scale + causal mask ----
        float sv0[4], sv1[4], mt[4];
        const bool need_mask = (k0 + 31 > Q0);   // wave-uniform
        #pragma unroll
        for (int r = 0; r < 4; ++r) {
            const int qrow = Q0 + quad * 4 + r;
            float a = s0[r] * scale;
            float c = s1[r] * scale;
            if (need_mask) {
                if (k0 + l16 > qrow)      a = -1e30f;
                if (k0 + 16 + l16 > qrow) c = -1e30f;
            }
            sv0[r] = a; sv1[r] = c;
            mt[r] = fmaxf(a, c);
        }
        // row-max across the 16 lanes of each quad
        #pragma unroll
        for (int off = 1; off <= 8; off <<= 1)
            #pragma unroll
            for (int r = 0; r < 4; ++r)
                mt[r] = fmaxf(mt[r], __shfl_xor(mt[r], off));

        float alpha[4], p0[4], p1[4], rs[4];
        #pragma unroll
        for (int r = 0; r < 4; ++r) {
            float mn = fmaxf(m_run[r], mt[r]);
            alpha[r] = __expf(m_run[r] - mn);
            m_run[r] = mn;
            p0[r] = __expf(sv0[r] - mn);
            p1[r] = __expf(sv1[r] - mn);
            rs[r] = p0[r] + p1[r];
        }
        #pragma unroll
        for (int off = 1; off <= 8; off <<= 1)
            #pragma unroll
            for (int r = 0; r < 4; ++r)
                rs[r] += __shfl_xor(rs[r], off);
        #pragma unroll
        for (int r = 0; r < 4; ++r)
            l_run[r] = l_run[r] * alpha[r] + rs[r];

        // ---- P (C-layout) -> LDS -> A-layout fragment ----
        #pragma unroll
        for (int r = 0; r < 4; ++r) {
            const int row = quad * 4 + r;
            Pw[row * 32 + l16]      = (unsigned short)f2bf(p0[r]);
            Pw[row * 32 + 16 + l16] = (unsigned short)f2bf(p1[r]);
        }
        __asm__ __volatile__("s_waitcnt lgkmcnt(0)" ::: "memory");
        short8 pf = *(const short8*)(Pw + (size_t)l16 * 32 + quad * 8);

        // ---- O = O*alpha + P·V over 24 channel tiles ----
        const short8* vp = (const short8*)(vB + (size_t)l16 * TSEQ + k0 + quad * 8);
        #pragma unroll
        for (int ct = 0; ct < 24; ++ct) {
            short8 vf = vp[ct * 16 * TSEQ / 8];   // ct*512 short8
            f32x4 a = acc[ct];
            #pragma unroll
            for (int r = 0; r < 4; ++r) a[r] *= alpha[r];
            acc[ct] = __builtin_amdgcn_mfma_f32_16x16x32_bf16(pf, vf, a, 0, 0, 0);
        }
    }

    // ---- epilogue: normalize, write bf16 row-major into Ob ----
    float inv[4];
    #pragma unroll
    for (int r = 0; r < 4; ++r) inv[r] = 1.f / l_run[r];
    #pragma unroll
    for (int ct = 0; ct < 24; ++ct) {
        #pragma unroll
        for (int r = 0; r < 4; ++r) {
            Ob[((size_t)b * TSEQ + Q0 + quad * 4 + r) * CEMB + ct * 16 + l16] =
                (unsigned short)f2bf(acc[ct][r] * inv[r]);
        }
    }
}

// ---------------------------------------------------------------------------
extern "C" void kernel_launch(void* const* d_in, const int* in_sizes, int n_in,
                              void* d_out, int out_size, void* d_ws, size_t ws_size,
                              hipStream_t stream)
{
    const float* x      = (const float*)d_in[0];
    const float* W_qkv  = (const float*)d_in[1];
    const float* b_qkv  = (const float*)d_in[2];
    const float* W_proj = (const float*)d_in[3];
    const float* b_proj = (const float*)d_in[4];
    float* out = (float*)d_out;

    const int Btot = 512;
    // per-batch ws (all bf16): xb + QKVb + Vt + Ob
    const size_t xb_pb  = (size_t)TSEQ * CEMB * 2;     // 196608
    const size_t qkv_pb = (size_t)TSEQ * QKV_LD * 2;   // 589824
    const size_t vt_pb  = (size_t)TSEQ * CEMB * 2;     // 196608
    const size_t ob_pb  = (size_t)TSEQ * CEMB * 2;     // 196608
    const size_t per_batch = xb_pb + qkv_pb + vt_pb + ob_pb;  // 1179648
    const size_t wq_sz = (size_t)CEMB * QKV_LD * 2;    // 884736
    const size_t wp_sz = (size_t)CEMB * CEMB * 2;      // 294912
    const size_t fixed = wq_sz + wp_sz;

    size_t avail = (ws_size > fixed) ? (ws_size - fixed) : 0;
    int chunk = (int)(avail / per_batch);
    if (chunk > Btot) chunk = Btot;
    if (chunk < 1) chunk = 1;
    if (chunk >= 8) chunk -= chunk % 8;   // enable XCD swizzle in attn

    char* p = (char*)d_ws;
    unsigned short* xb   = (unsigned short*)p;  p += xb_pb * chunk;
    unsigned short* QKVb = (unsigned short*)p;  p += qkv_pb * chunk;
    unsigned short* Vt   = (unsigned short*)p;  p += vt_pb * chunk;
    unsigned short* Ob   = (unsigned short*)p;  p += ob_pb * chunk;
    unsigned short* Wqt  = (unsigned short*)p;  p += wq_sz;
    unsigned short* Wpt  = (unsigned short*)p;

    // one-time weight cast+transpose (tiny)
    cast_wt_kernel<<<(CEMB * QKV_LD + 255) / 256, 256, 0, stream>>>(
        W_qkv, Wqt, CEMB, QKV_LD);
    cast_wt_kernel<<<(CEMB * CEMB + 255) / 256, 256, 0, stream>>>(
        W_proj, Wpt, CEMB, CEMB);

    for (int b0 = 0; b0 < Btot; b0 += chunk) {
        int cb = (chunk < Btot - b0) ? chunk : (Btot - b0);
        int Mc = cb * TSEQ;

        // cast x chunk to bf16
        int n8 = Mc * CEMB / 8;
        int gx = (n8 + 255) / 256;
        if (gx > 2048) gx = 2048;
        cast_x_kernel<<<gx, 256, 0, stream>>>(
            x + (size_t)b0 * TSEQ * CEMB, xb, n8);

        // QKV GEMM (bf16 MFMA): [Mc,384] x [1152,384]^T + bias -> QKVb bf16
        gemm_bf16_kernel<1><<<dim3(QKV_LD / 128, Mc / 128), 256, 0, stream>>>(
            xb, Wqt, b_qkv, QKVb, Mc, QKV_LD, CEMB);

        // V transpose (bf16 -> bf16)
        transpose_v_kernel<<<dim3(8, cb), 256, 0, stream>>>(QKVb, Vt);

        // flash attention (bf16 MFMA) -> Ob bf16 [Mc][384]
        int swz = (cb % 8 == 0) ? 1 : 0;
        attn_mfma_kernel<<<dim3(4 * cb), 256, 0, stream>>>(QKVb, Vt, Ob, swz);

        // proj GEMM (bf16 MFMA, fp32 out): [Mc,384] x [384,384]^T + bias
        gemm_bf16_kernel<0><<<dim3(CEMB / 128, Mc / 128), 256, 0, stream>>>(
            Ob, Wpt, b_proj, out + (size_t)b0 * TSEQ * CEMB, Mc, CEMB, CEMB);
    }
}

// Round 2
// 1117.919 us; speedup vs baseline: 1.1313x; 1.1313x over previous
//
#include <hip/hip_runtime.h>
#include <math.h>

#define TSEQ 256
#define CEMB 384
#define QK_LD 768      // q,k slots only (v split out at GEMM1 epilogue)
#define QKV_N 1152

typedef short short8 __attribute__((ext_vector_type(8)));
typedef short short4v __attribute__((ext_vector_type(4)));
typedef float f32x4 __attribute__((ext_vector_type(4)));

// fp32 -> bf16 bits, round-to-nearest-even (finite values only).
static __device__ __forceinline__ short f2bf(float f) {
    union { float f; unsigned u; } a;
    a.f = f;
    unsigned u = a.u + 0x7fffu + ((a.u >> 16) & 1u);
    return (short)(u >> 16);
}

// global -> LDS direct DMA, 16 bytes per lane. LDS dest is wave-uniform base;
// HW adds lane*16. Global address is per-lane.
static __device__ __forceinline__ void gload_lds16(const unsigned short* g,
                                                   unsigned short* l) {
    __builtin_amdgcn_global_load_lds(
        (const __attribute__((address_space(1))) unsigned int*)g,
        (__attribute__((address_space(3))) unsigned int*)l, 16, 0, 0);
}

// ---------------------------------------------------------------------------
// cast x (fp32) -> bf16, vectorized 8-wide
// ---------------------------------------------------------------------------
__global__ __launch_bounds__(256) void cast_x_kernel(
    const float* __restrict__ x, unsigned short* __restrict__ xb, int n8)
{
    int i = blockIdx.x * 256 + threadIdx.x;
    const int stride = gridDim.x * 256;
    for (; i < n8; i += stride) {
        const float* s = x + (size_t)i * 8;
        float4 a = *(const float4*)(s);
        float4 c = *(const float4*)(s + 4);
        short8 o;
        o[0] = f2bf(a.x); o[1] = f2bf(a.y); o[2] = f2bf(a.z); o[3] = f2bf(a.w);
        o[4] = f2bf(c.x); o[5] = f2bf(c.y); o[6] = f2bf(c.z); o[7] = f2bf(c.w);
        *(short8*)(xb + (size_t)i * 8) = o;
    }
}

// ---------------------------------------------------------------------------
// cast + transpose weights: Wt[n*K + k] = bf16(W[k*N + n]).  Tiny, once.
// ---------------------------------------------------------------------------
__global__ __launch_bounds__(256) void cast_wt_kernel(
    const float* __restrict__ W, unsigned short* __restrict__ Wt, int K, int N)
{
    int i = blockIdx.x * 256 + threadIdx.x;
    if (i < K * N) {
        int n = i / K;
        int k = i - n * K;
        Wt[i] = (unsigned short)f2bf(W[(size_t)k * N + n]);
    }
}

// ---------------------------------------------------------------------------
// bf16 MFMA GEMM (B pre-transposed), 2-phase double-buffered pipeline:
//   prologue STAGE(tile0); loop { STAGE(next); compute(cur); barrier; }
// One barrier + one vmcnt drain per K-step (via __syncthreads) instead of two.
// 128x128 tile, BK=32, 4 waves each computing a 64x64 sub-tile.
// MODE 0: fp32 out [M][N].
// MODE 1 (QKV): n<768 -> bf16 out QKb ld=768; n>=768 -> V written TRANSPOSED
//   into Vt[b][c][t] (packed short4 along t), folding the old transpose kernel.
// ---------------------------------------------------------------------------
template <int MODE>
__global__ __launch_bounds__(256) void gemm_bf16_kernel(
    const unsigned short* __restrict__ A, const unsigned short* __restrict__ Bt,
    const float* __restrict__ bias, void* __restrict__ Cout,
    unsigned short* __restrict__ Vt, int M, int N, int K)
{
    __shared__ unsigned short As[2][128 * 32];
    __shared__ unsigned short Bs[2][128 * 32];

    const int tid  = threadIdx.x;
    const int wave = tid >> 6;
    const int lane = tid & 63;
    const int quad = lane >> 4;
    const int l16  = lane & 15;
    const int wr   = wave >> 1;       // wave row 0..1
    const int wc   = wave & 1;        // wave col 0..1

    const int n0 = blockIdx.x * 128;
    const int m0 = blockIdx.y * 128;

    const int srow = tid >> 2;
    const int scol = (tid & 3) * 8;
    const unsigned short* Abase = A  + (size_t)(m0 + srow) * K + scol;
    const unsigned short* Bbase = Bt + (size_t)(n0 + srow) * K + scol;
    const int woff = wave << 9;       // wave*512 shorts

    f32x4 acc[4][4];
    #pragma unroll
    for (int mi = 0; mi < 4; ++mi)
        #pragma unroll
        for (int ni = 0; ni < 4; ++ni) acc[mi][ni] = (f32x4){0.f, 0.f, 0.f, 0.f};

    // prologue: stage tile 0
    gload_lds16(Abase, &As[0][woff]);
    gload_lds16(Abase + (size_t)64 * K, &As[0][2048 + woff]);
    gload_lds16(Bbase, &Bs[0][woff]);
    gload_lds16(Bbase + (size_t)64 * K, &Bs[0][2048 + woff]);
    __syncthreads();

    int cur = 0;
    for (int kk = 32; kk < K; kk += 32) {
        // stage next tile into the other buffer (overlaps with compute below)
        gload_lds16(Abase + kk, &As[cur ^ 1][woff]);
        gload_lds16(Abase + (size_t)64 * K + kk, &As[cur ^ 1][2048 + woff]);
        gload_lds16(Bbase + kk, &Bs[cur ^ 1][woff]);
        gload_lds16(Bbase + (size_t)64 * K + kk, &Bs[cur ^ 1][2048 + woff]);

        short8 af[4], bfr[4];
        #pragma unroll
        for (int mi = 0; mi < 4; ++mi)
            af[mi] = *(const short8*)&As[cur][(wr * 64 + mi * 16 + l16) * 32 + quad * 8];
        #pragma unroll
        for (int ni = 0; ni < 4; ++ni)
            bfr[ni] = *(const short8*)&Bs[cur][(wc * 64 + ni * 16 + l16) * 32 + quad * 8];
        #pragma unroll
        for (int mi = 0; mi < 4; ++mi)
            #pragma unroll
            for (int ni = 0; ni < 4; ++ni)
                acc[mi][ni] = __builtin_amdgcn_mfma_f32_16x16x32_bf16(
                    af[mi], bfr[ni], acc[mi][ni], 0, 0, 0);

        __syncthreads();   // drains vmcnt (stage done) + all reads of cur done
        cur ^= 1;
    }
    {   // epilogue tile (no stage)
        short8 af[4], bfr[4];
        #pragma unroll
        for (int mi = 0; mi < 4; ++mi)
            af[mi] = *(const short8*)&As[cur][(wr * 64 + mi * 16 + l16) * 32 + quad * 8];
        #pragma unroll
        for (int ni = 0; ni < 4; ++ni)
            bfr[ni] = *(const short8*)&Bs[cur][(wc * 64 + ni * 16 + l16) * 32 + quad * 8];
        #pragma unroll
        for (int mi = 0; mi < 4; ++mi)
            #pragma unroll
            for (int ni = 0; ni < 4; ++ni)
                acc[mi][ni] = __builtin_amdgcn_mfma_f32_16x16x32_bf16(
                    af[mi], bfr[ni], acc[mi][ni], 0, 0, 0);
    }

    if (MODE == 1 && n0 >= 768) {
        // V block: write transposed into Vt[b][c][t], 4 bf16 packed along t
        #pragma unroll
        for (int ni = 0; ni < 4; ++ni) {
            const int n = n0 + wc * 64 + ni * 16 + l16;
            const float bv = bias[n];
            const int c = n - 768;
            #pragma unroll
            for (int mi = 0; mi < 4; ++mi) {
                const int m = m0 + wr * 64 + mi * 16 + quad * 4;
                const int bb = m >> 8;
                const int t  = m & 255;
                short4v o;
                #pragma unroll
                for (int r = 0; r < 4; ++r)
                    o[r] = f2bf(acc[mi][ni][r] + bv);
                *(short4v*)(Vt + ((size_t)bb * CEMB + c) * TSEQ + t) = o;
            }
        }
        return;
    }

    #pragma unroll
    for (int ni = 0; ni < 4; ++ni) {
        const int n = n0 + wc * 64 + ni * 16 + l16;
        const float bv = bias[n];
        #pragma unroll
        for (int mi = 0; mi < 4; ++mi) {
            #pragma unroll
            for (int r = 0; r < 4; ++r) {
                const int m = m0 + wr * 64 + mi * 16 + quad * 4 + r;
                float v = acc[mi][ni][r] + bv;
                if (MODE == 1)
                    ((unsigned short*)Cout)[(size_t)m * QK_LD + n] = (unsigned short)f2bf(v);
                else
                    ((float*)Cout)[(size_t)m * N + n] = v;
            }
        }
    }
}

// ---------------------------------------------------------------------------
// Attention, full-S two-phase (non-online softmax; SEQ=256 fits in regs).
// One wave = one 16-row Q strip; block = 4 waves = 64 q rows of one batch.
// Phase 1: accumulate whole S strip (16 indep 16x16 acc tiles) -> huge MLP.
// Phase 2: single softmax pass (scale, causal mask, one shuffle-reduce).
// Phase 3: P -> padded LDS once, PV with 8 reused P-frags x 24 channel tiles.
// MFMA layouts (m89/m97-verified): A[l16][quad*8+j], B[quad*8+j][l16],
// C/D row=quad*4+r col=l16.
// ---------------------------------------------------------------------------
__global__ __launch_bounds__(256, 2) void attn_mfma_kernel(
    const unsigned short* __restrict__ QKb, const unsigned short* __restrict__ Vt,
    unsigned short* __restrict__ Ob, int swizzle)
{
    int bid = blockIdx.x;
    int b, g;
    if (swizzle) {   // keep one batch's 4 blocks on one XCD (round-robin assumption)
        g = (bid >> 3) & 3;
        b = ((bid >> 5) << 3) | (bid & 7);
    } else {
        b = bid >> 2;
        g = bid & 3;
    }
    const int wave = threadIdx.x >> 6;
    const int lane = threadIdx.x & 63;
    const int quad = lane >> 4;
    const int l16  = lane & 15;
    const int Q0   = g * 64 + wave * 16;       // this wave's first q row
    const int kcnt = Q0 + 16;                  // causal: cols 0..Q0+15
    const int NT   = kcnt >> 4;                // 16-wide S tiles (Q0 mult of 16)
    const int NKT32  = (NT + 1) >> 1;          // 32-wide PV k-tiles
    const int padcnt = NKT32 * 32;             // P cols incl zero padding

    // P strip per wave: [16 rows][264 cols] (pad 264 -> 528B rows, 16B-aligned,
    // bank-conflict-free-ish reads)
    __shared__ unsigned short Pbuf[4][16 * 264];
    unsigned short* Pw = &Pbuf[wave][0];

    const float scale = 0.051031036307982884f;  // 1/sqrt(384)

    // ---- Q fragments (A-operand), bf16 from QKb ----
    const unsigned short* qbase = QKb + ((size_t)b * TSEQ + Q0) * QK_LD;
    short8 qf[12];
    #pragma unroll
    for (int f = 0; f < 12; ++f)
        qf[f] = *(const short8*)(qbase + (size_t)l16 * QK_LD + f * 32 + quad * 8);

    // ---- phase 1: full S strip, 16 independent acc tiles ----
    f32x4 s[16];
    #pragma unroll
    for (int t = 0; t < 16; ++t) s[t] = (f32x4){0.f, 0.f, 0.f, 0.f};

    const unsigned short* kB = QKb + (size_t)b * TSEQ * QK_LD + CEMB;  // k slot
    #pragma unroll
    for (int t = 0; t < 16; ++t) {
        if (t * 16 < kcnt) {   // wave-uniform guard, static index after unroll
            const unsigned short* kp = kB + (size_t)(t * 16 + l16) * QK_LD + quad * 8;
            #pragma unroll
            for (int f = 0; f < 12; ++f) {
                short8 kf = *(const short8*)(kp + f * 32);
                s[t] = __builtin_amdgcn_mfma_f32_16x16x32_bf16(qf[f], kf, s[t], 0, 0, 0);
            }
        }
    }

    // ---- phase 2: scale + causal mask + single softmax pass ----
    float mt[4] = {-1e30f, -1e30f, -1e30f, -1e30f};
    #pragma unroll
    for (int t = 0; t < 16; ++t) {
        if (t * 16 < kcnt) {
            #pragma unroll
            for (int r = 0; r < 4; ++r) {
                const int qrow = Q0 + quad * 4 + r;
                float v = s[t][r] * scale;
                if (t * 16 + l16 > qrow) v = -1e30f;
                s[t][r] = v;
                mt[r] = fmaxf(mt[r], v);
            }
        }
    }
    #pragma unroll
    for (int off = 1; off <= 8; off <<= 1)
        #pragma unroll
        for (int r = 0; r < 4; ++r)
            mt[r] = fmaxf(mt[r], __shfl_xor(mt[r], off));

    float lr[4] = {0.f, 0.f, 0.f, 0.f};
    #pragma unroll
    for (int t = 0; t < 16; ++t) {
        if (t * 16 < kcnt) {
            #pragma unroll
            for (int r = 0; r < 4; ++r) {
                float p = __expf(s[t][r] - mt[r]);
                s[t][r] = p;
                lr[r] += p;
            }
        }
    }
    #pragma unroll
    for (int off = 1; off <= 8; off <<= 1)
        #pragma unroll
        for (int r = 0; r < 4; ++r)
            lr[r] += __shfl_xor(lr[r], off);

    // ---- P (C-layout) -> LDS once; zero-fill pad half-tile if NT odd ----
    #pragma unroll
    for (int t = 0; t < 16; ++t) {
        if (t * 16 < padcnt) {
            #pragma unroll
            for (int r = 0; r < 4; ++r) {
                float pv = (t * 16 < kcnt) ? s[t][r] : 0.f;
                Pw[(quad * 4 + r) * 264 + t * 16 + l16] = (unsigned short)f2bf(pv);
            }
        }
    }
    __asm__ __volatile__("s_waitcnt lgkmcnt(0)" ::: "memory");

    // ---- phase 3: PV.  8 P-frags loaded once, reused across 24 ct tiles ----
    short8 pf[8];
    #pragma unroll
    for (int kt = 0; kt < 8; ++kt)
        if (kt < NKT32)
            pf[kt] = *(const short8*)(Pw + (size_t)l16 * 264 + kt * 32 + quad * 8);

    f32x4 o[24];
    #pragma unroll
    for (int ct = 0; ct < 24; ++ct) o[ct] = (f32x4){0.f, 0.f, 0.f, 0.f};

    const unsigned short* vB = Vt + (size_t)b * CEMB * TSEQ;
    #pragma unroll
    for (int ct = 0; ct < 24; ++ct) {
        const unsigned short* vp = vB + (size_t)(ct * 16 + l16) * TSEQ + quad * 8;
        #pragma unroll
        for (int kt = 0; kt < 8; ++kt) {
            if (kt < NKT32) {
                short8 vf = *(const short8*)(vp + kt * 32);
                o[ct] = __builtin_amdgcn_mfma_f32_16x16x32_bf16(pf[kt], vf, o[ct], 0, 0, 0);
            }
        }
    }

    // ---- epilogue: normalize, bf16 row-major into Ob ----
    float inv[4];
    #pragma unroll
    for (int r = 0; r < 4; ++r) inv[r] = 1.f / lr[r];
    #pragma unroll
    for (int ct = 0; ct < 24; ++ct) {
        #pragma unroll
        for (int r = 0; r < 4; ++r) {
            Ob[((size_t)b * TSEQ + Q0 + quad * 4 + r) * CEMB + ct * 16 + l16] =
                (unsigned short)f2bf(o[ct][r] * inv[r]);
        }
    }
}

// ---------------------------------------------------------------------------
extern "C" void kernel_launch(void* const* d_in, const int* in_sizes, int n_in,
                              void* d_out, int out_size, void* d_ws, size_t ws_size,
                              hipStream_t stream)
{
    const float* x      = (const float*)d_in[0];
    const float* W_qkv  = (const float*)d_in[1];
    const float* b_qkv  = (const float*)d_in[2];
    const float* W_proj = (const float*)d_in[3];
    const float* b_proj = (const float*)d_in[4];
    float* out = (float*)d_out;

    const int Btot = 512;
    // per-batch ws (all bf16): xb + QKb(q,k only) + Vt + Ob
    const size_t xb_pb  = (size_t)TSEQ * CEMB * 2;     // 196608
    const size_t qkb_pb = (size_t)TSEQ * QK_LD * 2;    // 393216
    const size_t vt_pb  = (size_t)TSEQ * CEMB * 2;     // 196608
    const size_t ob_pb  = (size_t)TSEQ * CEMB * 2;     // 196608
    const size_t per_batch = xb_pb + qkb_pb + vt_pb + ob_pb;  // 983040
    const size_t wq_sz = (size_t)CEMB * QKV_N * 2;     // 884736
    const size_t wp_sz = (size_t)CEMB * CEMB * 2;      // 294912
    const size_t fixed = wq_sz + wp_sz;

    size_t avail = (ws_size > fixed) ? (ws_size - fixed) : 0;
    int chunk = (int)(avail / per_batch);
    if (chunk > Btot) chunk = Btot;
    if (chunk < 1) chunk = 1;
    if (chunk >= 8) chunk -= chunk % 8;   // enable XCD swizzle in attn

    char* p = (char*)d_ws;
    unsigned short* xb  = (unsigned short*)p;  p += xb_pb * chunk;
    unsigned short* QKb = (unsigned short*)p;  p += qkb_pb * chunk;
    unsigned short* Vt  = (unsigned short*)p;  p += vt_pb * chunk;
    unsigned short* Ob  = (unsigned short*)p;  p += ob_pb * chunk;
    unsigned short* Wqt = (unsigned short*)p;  p += wq_sz;
    unsigned short* Wpt = (unsigned short*)p;

    // one-time weight cast+transpose (tiny)
    cast_wt_kernel<<<(CEMB * QKV_N + 255) / 256, 256, 0, stream>>>(
        W_qkv, Wqt, CEMB, QKV_N);
    cast_wt_kernel<<<(CEMB * CEMB + 255) / 256, 256, 0, stream>>>(
        W_proj, Wpt, CEMB, CEMB);

    for (int b0 = 0; b0 < Btot; b0 += chunk) {
        int cb = (chunk < Btot - b0) ? chunk : (Btot - b0);
        int Mc = cb * TSEQ;

        // cast x chunk to bf16
        int n8 = Mc * CEMB / 8;
        int gx = (n8 + 255) / 256;
        if (gx > 2048) gx = 2048;
        cast_x_kernel<<<gx, 256, 0, stream>>>(
            x + (size_t)b0 * TSEQ * CEMB, xb, n8);

        // QKV GEMM (bf16 MFMA, 2-phase): q/k -> QKb bf16 ld=768,
        // v -> Vt transposed (folds old transpose kernel)
        gemm_bf16_kernel<1><<<dim3(QKV_N / 128, Mc / 128), 256, 0, stream>>>(
            xb, Wqt, b_qkv, QKb, Vt, Mc, QKV_N, CEMB);

        // attention (full-S two-phase) -> Ob bf16 [Mc][384]
        int swz = (cb % 8 == 0) ? 1 : 0;
        attn_mfma_kernel<<<dim3(4 * cb), 256, 0, stream>>>(QKb, Vt, Ob, swz);

        // proj GEMM (bf16 MFMA, 2-phase, fp32 out)
        gemm_bf16_kernel<0><<<dim3(CEMB / 128, Mc / 128), 256, 0, stream>>>(
            Ob, Wpt, b_proj, out + (size_t)b0 * TSEQ * CEMB, nullptr, Mc, CEMB, CEMB);
    }
}

// Round 3
// 1045.749 us; speedup vs baseline: 1.2094x; 1.0690x over previous
//
#include <hip/hip_runtime.h>
#include <math.h>

#define TSEQ 256
#define CEMB 384
#define QK_LD 768      // q,k slots only (v split out at GEMM1 epilogue)
#define QKV_N 1152

typedef short short8 __attribute__((ext_vector_type(8)));
typedef short short4v __attribute__((ext_vector_type(4)));
typedef float f32x4 __attribute__((ext_vector_type(4)));

// fp32 -> bf16 bits, round-to-nearest-even (finite values only).
static __device__ __forceinline__ short f2bf(float f) {
    union { float f; unsigned u; } a;
    a.f = f;
    unsigned u = a.u + 0x7fffu + ((a.u >> 16) & 1u);
    return (short)(u >> 16);
}

// global -> LDS direct DMA, 16 bytes per lane. LDS dest is wave-uniform base;
// HW adds lane*16. Global address is per-lane.
static __device__ __forceinline__ void gload_lds16(const unsigned short* g,
                                                   unsigned short* l) {
    __builtin_amdgcn_global_load_lds(
        (const __attribute__((address_space(1))) unsigned int*)g,
        (__attribute__((address_space(3))) unsigned int*)l, 16, 0, 0);
}

// ---------------------------------------------------------------------------
// cast x (fp32) -> bf16, vectorized 8-wide
// ---------------------------------------------------------------------------
__global__ __launch_bounds__(256) void cast_x_kernel(
    const float* __restrict__ x, unsigned short* __restrict__ xb, int n8)
{
    int i = blockIdx.x * 256 + threadIdx.x;
    const int stride = gridDim.x * 256;
    for (; i < n8; i += stride) {
        const float* s = x + (size_t)i * 8;
        float4 a = *(const float4*)(s);
        float4 c = *(const float4*)(s + 4);
        short8 o;
        o[0] = f2bf(a.x); o[1] = f2bf(a.y); o[2] = f2bf(a.z); o[3] = f2bf(a.w);
        o[4] = f2bf(c.x); o[5] = f2bf(c.y); o[6] = f2bf(c.z); o[7] = f2bf(c.w);
        *(short8*)(xb + (size_t)i * 8) = o;
    }
}

// ---------------------------------------------------------------------------
// cast + transpose weights: Wt[n*K + k] = bf16(W[k*N + n]).  Tiny, once.
// ---------------------------------------------------------------------------
__global__ __launch_bounds__(256) void cast_wt_kernel(
    const float* __restrict__ W, unsigned short* __restrict__ Wt, int K, int N)
{
    int i = blockIdx.x * 256 + threadIdx.x;
    if (i < K * N) {
        int n = i / K;
        int k = i - n * K;
        Wt[i] = (unsigned short)f2bf(W[(size_t)k * N + n]);
    }
}

// ---------------------------------------------------------------------------
// bf16 MFMA GEMM (B pre-transposed), 2-phase double-buffered pipeline.
// 128x128 tile, BK=32, 4 waves each computing a 64x64 sub-tile.
// XCD chunk-swizzle (m204, nwg%8==0): contiguous work ids per XCD so blocks
// sharing an A-panel row hit the same L2.
// MODE 0: fp32 out [M][N].
// MODE 1 (QKV): n<768 -> bf16 out QKb ld=768; n>=768 -> V written TRANSPOSED
//   into Vt[b][c][t] (packed short4 along t).
// ---------------------------------------------------------------------------
template <int MODE>
__global__ __launch_bounds__(256) void gemm_bf16_kernel(
    const unsigned short* __restrict__ A, const unsigned short* __restrict__ Bt,
    const float* __restrict__ bias, void* __restrict__ Cout,
    unsigned short* __restrict__ Vt, int M, int N, int K)
{
    __shared__ unsigned short As[2][128 * 32];
    __shared__ unsigned short Bs[2][128 * 32];

    const int tid  = threadIdx.x;
    const int wave = tid >> 6;
    const int lane = tid & 63;
    const int quad = lane >> 4;
    const int l16  = lane & 15;
    const int wr   = wave >> 1;       // wave row 0..1
    const int wc   = wave & 1;        // wave col 0..1

    // XCD-aware remap of the flat block id (HW round-robins bid%8 over XCDs)
    const int gx  = gridDim.x;
    const int nwg = gridDim.x * gridDim.y;
    int bid = blockIdx.y * gx + blockIdx.x;
    if ((nwg & 7) == 0) bid = (bid & 7) * (nwg >> 3) + (bid >> 3);
    const int n0 = (bid % gx) * 128;
    const int m0 = (bid / gx) * 128;

    const int srow = tid >> 2;
    const int scol = (tid & 3) * 8;
    const unsigned short* Abase = A  + (size_t)(m0 + srow) * K + scol;
    const unsigned short* Bbase = Bt + (size_t)(n0 + srow) * K + scol;
    const int woff = wave << 9;       // wave*512 shorts

    f32x4 acc[4][4];
    #pragma unroll
    for (int mi = 0; mi < 4; ++mi)
        #pragma unroll
        for (int ni = 0; ni < 4; ++ni) acc[mi][ni] = (f32x4){0.f, 0.f, 0.f, 0.f};

    // prologue: stage tile 0
    gload_lds16(Abase, &As[0][woff]);
    gload_lds16(Abase + (size_t)64 * K, &As[0][2048 + woff]);
    gload_lds16(Bbase, &Bs[0][woff]);
    gload_lds16(Bbase + (size_t)64 * K, &Bs[0][2048 + woff]);
    __syncthreads();

    int cur = 0;
    for (int kk = 32; kk < K; kk += 32) {
        gload_lds16(Abase + kk, &As[cur ^ 1][woff]);
        gload_lds16(Abase + (size_t)64 * K + kk, &As[cur ^ 1][2048 + woff]);
        gload_lds16(Bbase + kk, &Bs[cur ^ 1][woff]);
        gload_lds16(Bbase + (size_t)64 * K + kk, &Bs[cur ^ 1][2048 + woff]);

        short8 af[4], bfr[4];
        #pragma unroll
        for (int mi = 0; mi < 4; ++mi)
            af[mi] = *(const short8*)&As[cur][(wr * 64 + mi * 16 + l16) * 32 + quad * 8];
        #pragma unroll
        for (int ni = 0; ni < 4; ++ni)
            bfr[ni] = *(const short8*)&Bs[cur][(wc * 64 + ni * 16 + l16) * 32 + quad * 8];
        #pragma unroll
        for (int mi = 0; mi < 4; ++mi)
            #pragma unroll
            for (int ni = 0; ni < 4; ++ni)
                acc[mi][ni] = __builtin_amdgcn_mfma_f32_16x16x32_bf16(
                    af[mi], bfr[ni], acc[mi][ni], 0, 0, 0);

        __syncthreads();   // drains vmcnt (stage done) + all reads of cur done
        cur ^= 1;
    }
    {   // epilogue tile (no stage)
        short8 af[4], bfr[4];
        #pragma unroll
        for (int mi = 0; mi < 4; ++mi)
            af[mi] = *(const short8*)&As[cur][(wr * 64 + mi * 16 + l16) * 32 + quad * 8];
        #pragma unroll
        for (int ni = 0; ni < 4; ++ni)
            bfr[ni] = *(const short8*)&Bs[cur][(wc * 64 + ni * 16 + l16) * 32 + quad * 8];
        #pragma unroll
        for (int mi = 0; mi < 4; ++mi)
            #pragma unroll
            for (int ni = 0; ni < 4; ++ni)
                acc[mi][ni] = __builtin_amdgcn_mfma_f32_16x16x32_bf16(
                    af[mi], bfr[ni], acc[mi][ni], 0, 0, 0);
    }

    if (MODE == 1 && n0 >= 768) {
        // V block: write transposed into Vt[b][c][t], 4 bf16 packed along t
        #pragma unroll
        for (int ni = 0; ni < 4; ++ni) {
            const int n = n0 + wc * 64 + ni * 16 + l16;
            const float bv = bias[n];
            const int c = n - 768;
            #pragma unroll
            for (int mi = 0; mi < 4; ++mi) {
                const int m = m0 + wr * 64 + mi * 16 + quad * 4;
                const int bb = m >> 8;
                const int t  = m & 255;
                short4v o;
                #pragma unroll
                for (int r = 0; r < 4; ++r)
                    o[r] = f2bf(acc[mi][ni][r] + bv);
                *(short4v*)(Vt + ((size_t)bb * CEMB + c) * TSEQ + t) = o;
            }
        }
        return;
    }

    #pragma unroll
    for (int ni = 0; ni < 4; ++ni) {
        const int n = n0 + wc * 64 + ni * 16 + l16;
        const float bv = bias[n];
        #pragma unroll
        for (int mi = 0; mi < 4; ++mi) {
            #pragma unroll
            for (int r = 0; r < 4; ++r) {
                const int m = m0 + wr * 64 + mi * 16 + quad * 4 + r;
                float v = acc[mi][ni][r] + bv;
                if (MODE == 1)
                    ((unsigned short*)Cout)[(size_t)m * QK_LD + n] = (unsigned short)f2bf(v);
                else
                    ((float*)Cout)[(size_t)m * N + n] = v;
            }
        }
    }
}

// ---------------------------------------------------------------------------
// Attention: ONE WAVE per block, one 16-row causal strip per block.
// grid = 16*cb blocks of 64 threads; work id (after XCD swizzle): b = id>>4,
// strip st = id&15. Fine-grained blocks absorb the causal imbalance; no
// barriers (single wave); small LDS (8.4 KB) keeps many blocks resident.
// Phase 1: full S strip (st+1 16-wide tiles, independent accs).
// Phase 2: single softmax pass.
// Phase 3: P -> padded LDS once; per ct tile: 8 V loads + 8 MFMA, then
// normalize + store immediately (one live f32x4 accumulator).
// MFMA layouts (m89/m97-verified): A[l16][quad*8+j], B[quad*8+j][l16],
// C/D row=quad*4+r col=l16.
// ---------------------------------------------------------------------------
__global__ __launch_bounds__(64) void attn_mfma_kernel(
    const unsigned short* __restrict__ QKb, const unsigned short* __restrict__ Vt,
    unsigned short* __restrict__ Ob)
{
    const int nwg = gridDim.x;            // 16*cb, always %8==0
    int bid = blockIdx.x;
    bid = (bid & 7) * (nwg >> 3) + (bid >> 3);   // bijective XCD chunk swizzle
    const int b  = bid >> 4;
    const int st = bid & 15;              // strip index 0..15

    const int lane = threadIdx.x;
    const int quad = lane >> 4;
    const int l16  = lane & 15;
    const int Q0   = st * 16;
    const int NT   = st + 1;              // 16-wide S tiles
    const int NKT32  = (NT + 1) >> 1;     // 32-wide PV k-tiles
    const int kcnt   = NT * 16;
    const int padcnt = NKT32 * 32;

    __shared__ unsigned short Pw[16 * 264];   // 16 rows x 264 cols (pad)

    const float scale = 0.051031036307982884f;  // 1/sqrt(384)

    // ---- Q fragments (A-operand) ----
    const unsigned short* qbase = QKb + ((size_t)b * TSEQ + Q0) * QK_LD;
    short8 qf[12];
    #pragma unroll
    for (int f = 0; f < 12; ++f)
        qf[f] = *(const short8*)(qbase + (size_t)l16 * QK_LD + f * 32 + quad * 8);

    // ---- phase 1: full S strip ----
    f32x4 s[16];
    #pragma unroll
    for (int t = 0; t < 16; ++t) s[t] = (f32x4){0.f, 0.f, 0.f, 0.f};

    const unsigned short* kB = QKb + (size_t)b * TSEQ * QK_LD + CEMB;  // k slot
    #pragma unroll
    for (int t = 0; t < 16; ++t) {
        if (t <= st) {   // block-uniform guard, static index after unroll
            const unsigned short* kp = kB + (size_t)(t * 16 + l16) * QK_LD + quad * 8;
            #pragma unroll
            for (int f = 0; f < 12; ++f) {
                short8 kf = *(const short8*)(kp + f * 32);
                s[t] = __builtin_amdgcn_mfma_f32_16x16x32_bf16(qf[f], kf, s[t], 0, 0, 0);
            }
        }
    }

    // ---- phase 2: scale + causal mask + single softmax pass ----
    float mt[4] = {-1e30f, -1e30f, -1e30f, -1e30f};
    #pragma unroll
    for (int t = 0; t < 16; ++t) {
        if (t <= st) {
            #pragma unroll
            for (int r = 0; r < 4; ++r) {
                const int qrow = Q0 + quad * 4 + r;
                float v = s[t][r] * scale;
                if (t * 16 + l16 > qrow) v = -1e30f;
                s[t][r] = v;
                mt[r] = fmaxf(mt[r], v);
            }
        }
    }
    #pragma unroll
    for (int off = 1; off <= 8; off <<= 1)
        #pragma unroll
        for (int r = 0; r < 4; ++r)
            mt[r] = fmaxf(mt[r], __shfl_xor(mt[r], off));

    float lr[4] = {0.f, 0.f, 0.f, 0.f};
    #pragma unroll
    for (int t = 0; t < 16; ++t) {
        if (t <= st) {
            #pragma unroll
            for (int r = 0; r < 4; ++r) {
                float p = __expf(s[t][r] - mt[r]);
                s[t][r] = p;
                lr[r] += p;
            }
        }
    }
    #pragma unroll
    for (int off = 1; off <= 8; off <<= 1)
        #pragma unroll
        for (int r = 0; r < 4; ++r)
            lr[r] += __shfl_xor(lr[r], off);
    float inv[4];
    #pragma unroll
    for (int r = 0; r < 4; ++r) inv[r] = 1.f / lr[r];

    // ---- P (C-layout) -> LDS once; zero-fill pad half-tile if NT odd ----
    #pragma unroll
    for (int t = 0; t < 16; ++t) {
        if (t * 16 < padcnt) {
            #pragma unroll
            for (int r = 0; r < 4; ++r) {
                float pv = (t <= st) ? s[t][r] : 0.f;
                Pw[(quad * 4 + r) * 264 + t * 16 + l16] = (unsigned short)f2bf(pv);
            }
        }
    }
    __asm__ __volatile__("s_waitcnt lgkmcnt(0)" ::: "memory");  // single wave: no barrier needed

    // ---- phase 3: PV. 8 P-frags loaded once, then per-ct accumulate+store ----
    short8 pf[8];
    #pragma unroll
    for (int kt = 0; kt < 8; ++kt)
        if (kt < NKT32)
            pf[kt] = *(const short8*)(Pw + (size_t)l16 * 264 + kt * 32 + quad * 8);

    const unsigned short* vB = Vt + (size_t)b * CEMB * TSEQ;
    unsigned short* obase = Ob + ((size_t)b * TSEQ + Q0) * CEMB;
    #pragma unroll 4
    for (int ct = 0; ct < 24; ++ct) {
        const unsigned short* vp = vB + (size_t)(ct * 16 + l16) * TSEQ + quad * 8;
        f32x4 o = (f32x4){0.f, 0.f, 0.f, 0.f};
        #pragma unroll
        for (int kt = 0; kt < 8; ++kt) {
            if (kt < NKT32) {
                short8 vf = *(const short8*)(vp + kt * 32);
                o = __builtin_amdgcn_mfma_f32_16x16x32_bf16(pf[kt], vf, o, 0, 0, 0);
            }
        }
        #pragma unroll
        for (int r = 0; r < 4; ++r)
            obase[(size_t)(quad * 4 + r) * CEMB + ct * 16 + l16] =
                (unsigned short)f2bf(o[r] * inv[r]);
    }
}

// ---------------------------------------------------------------------------
extern "C" void kernel_launch(void* const* d_in, const int* in_sizes, int n_in,
                              void* d_out, int out_size, void* d_ws, size_t ws_size,
                              hipStream_t stream)
{
    const float* x      = (const float*)d_in[0];
    const float* W_qkv  = (const float*)d_in[1];
    const float* b_qkv  = (const float*)d_in[2];
    const float* W_proj = (const float*)d_in[3];
    const float* b_proj = (const float*)d_in[4];
    float* out = (float*)d_out;

    const int Btot = 512;
    // per-batch ws (all bf16): xb + QKb(q,k only) + Vt + Ob
    const size_t xb_pb  = (size_t)TSEQ * CEMB * 2;     // 196608
    const size_t qkb_pb = (size_t)TSEQ * QK_LD * 2;    // 393216
    const size_t vt_pb  = (size_t)TSEQ * CEMB * 2;     // 196608
    const size_t ob_pb  = (size_t)TSEQ * CEMB * 2;     // 196608
    const size_t per_batch = xb_pb + qkb_pb + vt_pb + ob_pb;  // 983040
    const size_t wq_sz = (size_t)CEMB * QKV_N * 2;     // 884736
    const size_t wp_sz = (size_t)CEMB * CEMB * 2;      // 294912
    const size_t fixed = wq_sz + wp_sz;

    size_t avail = (ws_size > fixed) ? (ws_size - fixed) : 0;
    int chunk = (int)(avail / per_batch);
    if (chunk > Btot) chunk = Btot;
    if (chunk < 1) chunk = 1;

    char* p = (char*)d_ws;
    unsigned short* xb  = (unsigned short*)p;  p += xb_pb * chunk;
    unsigned short* QKb = (unsigned short*)p;  p += qkb_pb * chunk;
    unsigned short* Vt  = (unsigned short*)p;  p += vt_pb * chunk;
    unsigned short* Ob  = (unsigned short*)p;  p += ob_pb * chunk;
    unsigned short* Wqt = (unsigned short*)p;  p += wq_sz;
    unsigned short* Wpt = (unsigned short*)p;

    // one-time weight cast+transpose (tiny)
    cast_wt_kernel<<<(CEMB * QKV_N + 255) / 256, 256, 0, stream>>>(
        W_qkv, Wqt, CEMB, QKV_N);
    cast_wt_kernel<<<(CEMB * CEMB + 255) / 256, 256, 0, stream>>>(
        W_proj, Wpt, CEMB, CEMB);

    for (int b0 = 0; b0 < Btot; b0 += chunk) {
        int cb = (chunk < Btot - b0) ? chunk : (Btot - b0);
        int Mc = cb * TSEQ;

        // cast x chunk to bf16
        int n8 = Mc * CEMB / 8;
        int gx = (n8 + 255) / 256;
        if (gx > 2048) gx = 2048;
        cast_x_kernel<<<gx, 256, 0, stream>>>(
            x + (size_t)b0 * TSEQ * CEMB, xb, n8);

        // QKV GEMM (bf16 MFMA, 2-phase): q/k -> QKb bf16 ld=768,
        // v -> Vt transposed
        gemm_bf16_kernel<1><<<dim3(QKV_N / 128, Mc / 128), 256, 0, stream>>>(
            xb, Wqt, b_qkv, QKb, Vt, Mc, QKV_N, CEMB);

        // attention: one wave per 16-row strip, 16*cb blocks of 64 threads
        attn_mfma_kernel<<<dim3(16 * cb), 64, 0, stream>>>(QKb, Vt, Ob);

        // proj GEMM (bf16 MFMA, 2-phase, fp32 out)
        gemm_bf16_kernel<0><<<dim3(CEMB / 128, Mc / 128), 256, 0, stream>>>(
            Ob, Wpt, b_proj, out + (size_t)b0 * TSEQ * CEMB, nullptr, Mc, CEMB, CEMB);
    }
}

// Round 4
// 873.563 us; speedup vs baseline: 1.4478x; 1.1971x over previous
//
#include <hip/hip_runtime.h>
#include <math.h>

#define TSEQ 256
#define CEMB 384
#define QK_LD 768      // q,k slots only (v split out at GEMM1 epilogue)
#define QKV_N 1152

typedef short short8 __attribute__((ext_vector_type(8)));
typedef short short4v __attribute__((ext_vector_type(4)));
typedef float f32x4 __attribute__((ext_vector_type(4)));

// fp32 -> bf16 bits, round-to-nearest-even (finite values only).
static __device__ __forceinline__ short f2bf(float f) {
    union { float f; unsigned u; } a;
    a.f = f;
    unsigned u = a.u + 0x7fffu + ((a.u >> 16) & 1u);
    return (short)(u >> 16);
}

// global -> LDS direct DMA, 16 bytes per lane. LDS dest is wave-uniform base;
// HW adds lane*16. Global address is per-lane.
static __device__ __forceinline__ void gload_lds16(const unsigned short* g,
                                                   unsigned short* l) {
    __builtin_amdgcn_global_load_lds(
        (const __attribute__((address_space(1))) unsigned int*)g,
        (__attribute__((address_space(3))) unsigned int*)l, 16, 0, 0);
}

// ---------------------------------------------------------------------------
// cast x (fp32) -> bf16, vectorized 8-wide
// ---------------------------------------------------------------------------
__global__ __launch_bounds__(256) void cast_x_kernel(
    const float* __restrict__ x, unsigned short* __restrict__ xb, int n8)
{
    int i = blockIdx.x * 256 + threadIdx.x;
    const int stride = gridDim.x * 256;
    for (; i < n8; i += stride) {
        const float* s = x + (size_t)i * 8;
        float4 a = *(const float4*)(s);
        float4 c = *(const float4*)(s + 4);
        short8 o;
        o[0] = f2bf(a.x); o[1] = f2bf(a.y); o[2] = f2bf(a.z); o[3] = f2bf(a.w);
        o[4] = f2bf(c.x); o[5] = f2bf(c.y); o[6] = f2bf(c.z); o[7] = f2bf(c.w);
        *(short8*)(xb + (size_t)i * 8) = o;
    }
}

// ---------------------------------------------------------------------------
// cast + transpose weights: Wt[n*K + k] = bf16(W[k*N + n]).  Tiny, once.
// ---------------------------------------------------------------------------
__global__ __launch_bounds__(256) void cast_wt_kernel(
    const float* __restrict__ W, unsigned short* __restrict__ Wt, int K, int N)
{
    int i = blockIdx.x * 256 + threadIdx.x;
    if (i < K * N) {
        int n = i / K;
        int k = i - n * K;
        Wt[i] = (unsigned short)f2bf(W[(size_t)k * N + n]);
    }
}

// ---------------------------------------------------------------------------
// bf16 MFMA GEMM (B pre-transposed), 2-phase double-buffered pipeline.
// 128x128 tile, BK=32, 4 waves each computing a 64x64 sub-tile.
// XCD chunk-swizzle (m204, nwg%8==0).
// MODE 0: fp32 out [M][N].
// MODE 1 (QKV): n<768 -> bf16 out QKb ld=768; n>=768 -> V written TRANSPOSED
//   into Vt[b][c][t] (packed short4 along t).
// ---------------------------------------------------------------------------
template <int MODE>
__global__ __launch_bounds__(256) void gemm_bf16_kernel(
    const unsigned short* __restrict__ A, const unsigned short* __restrict__ Bt,
    const float* __restrict__ bias, void* __restrict__ Cout,
    unsigned short* __restrict__ Vt, int M, int N, int K)
{
    __shared__ unsigned short As[2][128 * 32];
    __shared__ unsigned short Bs[2][128 * 32];

    const int tid  = threadIdx.x;
    const int wave = tid >> 6;
    const int lane = tid & 63;
    const int quad = lane >> 4;
    const int l16  = lane & 15;
    const int wr   = wave >> 1;
    const int wc   = wave & 1;

    const int gx  = gridDim.x;
    const int nwg = gridDim.x * gridDim.y;
    int bid = blockIdx.y * gx + blockIdx.x;
    if ((nwg & 7) == 0) bid = (bid & 7) * (nwg >> 3) + (bid >> 3);
    const int n0 = (bid % gx) * 128;
    const int m0 = (bid / gx) * 128;

    const int srow = tid >> 2;
    const int scol = (tid & 3) * 8;
    const unsigned short* Abase = A  + (size_t)(m0 + srow) * K + scol;
    const unsigned short* Bbase = Bt + (size_t)(n0 + srow) * K + scol;
    const int woff = wave << 9;

    f32x4 acc[4][4];
    #pragma unroll
    for (int mi = 0; mi < 4; ++mi)
        #pragma unroll
        for (int ni = 0; ni < 4; ++ni) acc[mi][ni] = (f32x4){0.f, 0.f, 0.f, 0.f};

    gload_lds16(Abase, &As[0][woff]);
    gload_lds16(Abase + (size_t)64 * K, &As[0][2048 + woff]);
    gload_lds16(Bbase, &Bs[0][woff]);
    gload_lds16(Bbase + (size_t)64 * K, &Bs[0][2048 + woff]);
    __syncthreads();

    int cur = 0;
    for (int kk = 32; kk < K; kk += 32) {
        gload_lds16(Abase + kk, &As[cur ^ 1][woff]);
        gload_lds16(Abase + (size_t)64 * K + kk, &As[cur ^ 1][2048 + woff]);
        gload_lds16(Bbase + kk, &Bs[cur ^ 1][woff]);
        gload_lds16(Bbase + (size_t)64 * K + kk, &Bs[cur ^ 1][2048 + woff]);

        short8 af[4], bfr[4];
        #pragma unroll
        for (int mi = 0; mi < 4; ++mi)
            af[mi] = *(const short8*)&As[cur][(wr * 64 + mi * 16 + l16) * 32 + quad * 8];
        #pragma unroll
        for (int ni = 0; ni < 4; ++ni)
            bfr[ni] = *(const short8*)&Bs[cur][(wc * 64 + ni * 16 + l16) * 32 + quad * 8];
        #pragma unroll
        for (int mi = 0; mi < 4; ++mi)
            #pragma unroll
            for (int ni = 0; ni < 4; ++ni)
                acc[mi][ni] = __builtin_amdgcn_mfma_f32_16x16x32_bf16(
                    af[mi], bfr[ni], acc[mi][ni], 0, 0, 0);

        __syncthreads();
        cur ^= 1;
    }
    {
        short8 af[4], bfr[4];
        #pragma unroll
        for (int mi = 0; mi < 4; ++mi)
            af[mi] = *(const short8*)&As[cur][(wr * 64 + mi * 16 + l16) * 32 + quad * 8];
        #pragma unroll
        for (int ni = 0; ni < 4; ++ni)
            bfr[ni] = *(const short8*)&Bs[cur][(wc * 64 + ni * 16 + l16) * 32 + quad * 8];
        #pragma unroll
        for (int mi = 0; mi < 4; ++mi)
            #pragma unroll
            for (int ni = 0; ni < 4; ++ni)
                acc[mi][ni] = __builtin_amdgcn_mfma_f32_16x16x32_bf16(
                    af[mi], bfr[ni], acc[mi][ni], 0, 0, 0);
    }

    if (MODE == 1 && n0 >= 768) {
        #pragma unroll
        for (int ni = 0; ni < 4; ++ni) {
            const int n = n0 + wc * 64 + ni * 16 + l16;
            const float bv = bias[n];
            const int c = n - 768;
            #pragma unroll
            for (int mi = 0; mi < 4; ++mi) {
                const int m = m0 + wr * 64 + mi * 16 + quad * 4;
                const int bb = m >> 8;
                const int t  = m & 255;
                short4v o;
                #pragma unroll
                for (int r = 0; r < 4; ++r)
                    o[r] = f2bf(acc[mi][ni][r] + bv);
                *(short4v*)(Vt + ((size_t)bb * CEMB + c) * TSEQ + t) = o;
            }
        }
        return;
    }

    #pragma unroll
    for (int ni = 0; ni < 4; ++ni) {
        const int n = n0 + wc * 64 + ni * 16 + l16;
        const float bv = bias[n];
        #pragma unroll
        for (int mi = 0; mi < 4; ++mi) {
            #pragma unroll
            for (int r = 0; r < 4; ++r) {
                const int m = m0 + wr * 64 + mi * 16 + quad * 4 + r;
                float v = acc[mi][ni][r] + bv;
                if (MODE == 1)
                    ((unsigned short*)Cout)[(size_t)m * QK_LD + n] = (unsigned short)f2bf(v);
                else
                    ((float*)Cout)[(size_t)m * N + n] = v;
            }
        }
    }
}

// ---------------------------------------------------------------------------
// QK^T batched GEMM: S[b][m][n] = sum_c Q[b][m][c] * K[b][n][c], f32 out.
// Only causal tiles: blockIdx.x 0->(0,0) 1->(1,0) 2->(1,1); blockIdx.y = b.
// No mask/scale here (softmax applies both). Same 2-phase pipeline.
// ---------------------------------------------------------------------------
__global__ __launch_bounds__(256) void qk_gemm_kernel(
    const unsigned short* __restrict__ QKb, float* __restrict__ S)
{
    const int tt = blockIdx.x;
    const int b  = blockIdx.y;
    const int ti = (tt >= 1) ? 1 : 0;
    const int tj = (tt == 2) ? 1 : 0;
    const int m0 = ti * 128, n0 = tj * 128;

    __shared__ unsigned short As[2][128 * 32];
    __shared__ unsigned short Bs[2][128 * 32];

    const int tid  = threadIdx.x;
    const int wave = tid >> 6;
    const int lane = tid & 63;
    const int quad = lane >> 4;
    const int l16  = lane & 15;
    const int wr   = wave >> 1;
    const int wc   = wave & 1;

    const int srow = tid >> 2;
    const int scol = (tid & 3) * 8;
    const unsigned short* Abase = QKb + ((size_t)b * TSEQ + m0 + srow) * QK_LD + scol;
    const unsigned short* Bbase = QKb + ((size_t)b * TSEQ + n0 + srow) * QK_LD + CEMB + scol;
    const int woff = wave << 9;

    f32x4 acc[4][4];
    #pragma unroll
    for (int mi = 0; mi < 4; ++mi)
        #pragma unroll
        for (int ni = 0; ni < 4; ++ni) acc[mi][ni] = (f32x4){0.f, 0.f, 0.f, 0.f};

    gload_lds16(Abase, &As[0][woff]);
    gload_lds16(Abase + (size_t)64 * QK_LD, &As[0][2048 + woff]);
    gload_lds16(Bbase, &Bs[0][woff]);
    gload_lds16(Bbase + (size_t)64 * QK_LD, &Bs[0][2048 + woff]);
    __syncthreads();

    int cur = 0;
    for (int kk = 32; kk < CEMB; kk += 32) {
        gload_lds16(Abase + kk, &As[cur ^ 1][woff]);
        gload_lds16(Abase + (size_t)64 * QK_LD + kk, &As[cur ^ 1][2048 + woff]);
        gload_lds16(Bbase + kk, &Bs[cur ^ 1][woff]);
        gload_lds16(Bbase + (size_t)64 * QK_LD + kk, &Bs[cur ^ 1][2048 + woff]);

        short8 af[4], bfr[4];
        #pragma unroll
        for (int mi = 0; mi < 4; ++mi)
            af[mi] = *(const short8*)&As[cur][(wr * 64 + mi * 16 + l16) * 32 + quad * 8];
        #pragma unroll
        for (int ni = 0; ni < 4; ++ni)
            bfr[ni] = *(const short8*)&Bs[cur][(wc * 64 + ni * 16 + l16) * 32 + quad * 8];
        #pragma unroll
        for (int mi = 0; mi < 4; ++mi)
            #pragma unroll
            for (int ni = 0; ni < 4; ++ni)
                acc[mi][ni] = __builtin_amdgcn_mfma_f32_16x16x32_bf16(
                    af[mi], bfr[ni], acc[mi][ni], 0, 0, 0);

        __syncthreads();
        cur ^= 1;
    }
    {
        short8 af[4], bfr[4];
        #pragma unroll
        for (int mi = 0; mi < 4; ++mi)
            af[mi] = *(const short8*)&As[cur][(wr * 64 + mi * 16 + l16) * 32 + quad * 8];
        #pragma unroll
        for (int ni = 0; ni < 4; ++ni)
            bfr[ni] = *(const short8*)&Bs[cur][(wc * 64 + ni * 16 + l16) * 32 + quad * 8];
        #pragma unroll
        for (int mi = 0; mi < 4; ++mi)
            #pragma unroll
            for (int ni = 0; ni < 4; ++ni)
                acc[mi][ni] = __builtin_amdgcn_mfma_f32_16x16x32_bf16(
                    af[mi], bfr[ni], acc[mi][ni], 0, 0, 0);
    }

    float* Sb = S + (size_t)b * TSEQ * TSEQ;
    #pragma unroll
    for (int ni = 0; ni < 4; ++ni) {
        const int n = n0 + wc * 64 + ni * 16 + l16;
        #pragma unroll
        for (int mi = 0; mi < 4; ++mi) {
            #pragma unroll
            for (int r = 0; r < 4; ++r) {
                const int m = m0 + wr * 64 + mi * 16 + quad * 4 + r;
                Sb[(size_t)m * TSEQ + n] = acc[mi][ni][r];
            }
        }
    }
}

// ---------------------------------------------------------------------------
// Row softmax: one wave per row. Mask (col>t), scale, exp(s-m); write
// unnormalized bf16 P (zeros padded through the row's causal tile coverage)
// and Linv[b][t] = 1/sum (applied in pv epilogue -> numerics identical to
// the previous fused kernel).
// ---------------------------------------------------------------------------
__global__ __launch_bounds__(256) void softmax_rows_kernel(
    const float* __restrict__ S, unsigned short* __restrict__ P,
    float* __restrict__ Linv)
{
    const int b    = blockIdx.y;
    const int t    = blockIdx.x * 4 + (threadIdx.x >> 6);
    const int lane = threadIdx.x & 63;
    const int col  = lane * 4;
    const int Kcov = ((t >> 7) + 1) * 128;   // causal tile coverage for this row
    const float scale = 0.051031036307982884f;  // 1/sqrt(384)

    const float* sp = S + ((size_t)b * TSEQ + t) * TSEQ;
    float v[4];
    if (col < Kcov) {
        float4 sv = *(const float4*)(sp + col);
        v[0] = (col + 0 <= t) ? sv.x * scale : -1e30f;
        v[1] = (col + 1 <= t) ? sv.y * scale : -1e30f;
        v[2] = (col + 2 <= t) ? sv.z * scale : -1e30f;
        v[3] = (col + 3 <= t) ? sv.w * scale : -1e30f;
    } else {
        v[0] = v[1] = v[2] = v[3] = -1e30f;
    }

    float m = fmaxf(fmaxf(v[0], v[1]), fmaxf(v[2], v[3]));
    #pragma unroll
    for (int off = 1; off <= 32; off <<= 1)
        m = fmaxf(m, __shfl_xor(m, off));

    float p[4];
    float s = 0.f;
    #pragma unroll
    for (int j = 0; j < 4; ++j) {
        p[j] = __expf(v[j] - m);
        s += p[j];
    }
    #pragma unroll
    for (int off = 1; off <= 32; off <<= 1)
        s += __shfl_xor(s, off);

    if (lane == 0) Linv[(size_t)b * TSEQ + t] = 1.f / s;

    if (col < Kcov) {
        short4v o;
        #pragma unroll
        for (int j = 0; j < 4; ++j) o[j] = f2bf(p[j]);
        *(short4v*)(P + ((size_t)b * TSEQ + t) * TSEQ + col) = o;
    }
}

// ---------------------------------------------------------------------------
// PV batched GEMM: Ob[b][m][c] = (sum_s P[b][m][s] * Vt[b][c][s]) * Linv[b][m].
// blockIdx.x = tile 0..5: ti = x/3 (m-block), tj = x%3 (channel block);
// K-extent = (ti+1)*128 (causal truncation). blockIdx.y = b. bf16 out.
// ---------------------------------------------------------------------------
__global__ __launch_bounds__(256) void pv_gemm_kernel(
    const unsigned short* __restrict__ P, const unsigned short* __restrict__ Vt,
    const float* __restrict__ Linv, unsigned short* __restrict__ Ob)
{
    const int tt = blockIdx.x;
    const int b  = blockIdx.y;
    const int ti = tt / 3;
    const int tj = tt - ti * 3;
    const int m0 = ti * 128, n0 = tj * 128;
    const int Kext = (ti + 1) * 128;

    __shared__ unsigned short As[2][128 * 32];
    __shared__ unsigned short Bs[2][128 * 32];

    const int tid  = threadIdx.x;
    const int wave = tid >> 6;
    const int lane = tid & 63;
    const int quad = lane >> 4;
    const int l16  = lane & 15;
    const int wr   = wave >> 1;
    const int wc   = wave & 1;

    const int srow = tid >> 2;
    const int scol = (tid & 3) * 8;
    const unsigned short* Abase = P  + ((size_t)b * TSEQ + m0 + srow) * TSEQ + scol;
    const unsigned short* Bbase = Vt + ((size_t)b * CEMB + n0 + srow) * TSEQ + scol;
    const int woff = wave << 9;

    f32x4 acc[4][4];
    #pragma unroll
    for (int mi = 0; mi < 4; ++mi)
        #pragma unroll
        for (int ni = 0; ni < 4; ++ni) acc[mi][ni] = (f32x4){0.f, 0.f, 0.f, 0.f};

    gload_lds16(Abase, &As[0][woff]);
    gload_lds16(Abase + (size_t)64 * TSEQ, &As[0][2048 + woff]);
    gload_lds16(Bbase, &Bs[0][woff]);
    gload_lds16(Bbase + (size_t)64 * TSEQ, &Bs[0][2048 + woff]);
    __syncthreads();

    int cur = 0;
    for (int kk = 32; kk < Kext; kk += 32) {
        gload_lds16(Abase + kk, &As[cur ^ 1][woff]);
        gload_lds16(Abase + (size_t)64 * TSEQ + kk, &As[cur ^ 1][2048 + woff]);
        gload_lds16(Bbase + kk, &Bs[cur ^ 1][woff]);
        gload_lds16(Bbase + (size_t)64 * TSEQ + kk, &Bs[cur ^ 1][2048 + woff]);

        short8 af[4], bfr[4];
        #pragma unroll
        for (int mi = 0; mi < 4; ++mi)
            af[mi] = *(const short8*)&As[cur][(wr * 64 + mi * 16 + l16) * 32 + quad * 8];
        #pragma unroll
        for (int ni = 0; ni < 4; ++ni)
            bfr[ni] = *(const short8*)&Bs[cur][(wc * 64 + ni * 16 + l16) * 32 + quad * 8];
        #pragma unroll
        for (int mi = 0; mi < 4; ++mi)
            #pragma unroll
            for (int ni = 0; ni < 4; ++ni)
                acc[mi][ni] = __builtin_amdgcn_mfma_f32_16x16x32_bf16(
                    af[mi], bfr[ni], acc[mi][ni], 0, 0, 0);

        __syncthreads();
        cur ^= 1;
    }
    {
        short8 af[4], bfr[4];
        #pragma unroll
        for (int mi = 0; mi < 4; ++mi)
            af[mi] = *(const short8*)&As[cur][(wr * 64 + mi * 16 + l16) * 32 + quad * 8];
        #pragma unroll
        for (int ni = 0; ni < 4; ++ni)
            bfr[ni] = *(const short8*)&Bs[cur][(wc * 64 + ni * 16 + l16) * 32 + quad * 8];
        #pragma unroll
        for (int mi = 0; mi < 4; ++mi)
            #pragma unroll
            for (int ni = 0; ni < 4; ++ni)
                acc[mi][ni] = __builtin_amdgcn_mfma_f32_16x16x32_bf16(
                    af[mi], bfr[ni], acc[mi][ni], 0, 0, 0);
    }

    const float* lv = Linv + (size_t)b * TSEQ;
    unsigned short* ob = Ob + (size_t)b * TSEQ * CEMB;
    #pragma unroll
    for (int mi = 0; mi < 4; ++mi) {
        #pragma unroll
        for (int r = 0; r < 4; ++r) {
            const int m = m0 + wr * 64 + mi * 16 + quad * 4 + r;
            const float inv = lv[m];
            #pragma unroll
            for (int ni = 0; ni < 4; ++ni) {
                const int n = n0 + wc * 64 + ni * 16 + l16;
                ob[(size_t)m * CEMB + n] = (unsigned short)f2bf(acc[mi][ni][r] * inv);
            }
        }
    }
}

// ---------------------------------------------------------------------------
extern "C" void kernel_launch(void* const* d_in, const int* in_sizes, int n_in,
                              void* d_out, int out_size, void* d_ws, size_t ws_size,
                              hipStream_t stream)
{
    const float* x      = (const float*)d_in[0];
    const float* W_qkv  = (const float*)d_in[1];
    const float* b_qkv  = (const float*)d_in[2];
    const float* W_proj = (const float*)d_in[3];
    const float* b_proj = (const float*)d_in[4];
    float* out = (float*)d_out;

    const int Btot = 512;
    const size_t xb_pb   = (size_t)TSEQ * CEMB * 2;     // 196608
    const size_t qkb_pb  = (size_t)TSEQ * QK_LD * 2;    // 393216
    const size_t vt_pb   = (size_t)TSEQ * CEMB * 2;     // 196608
    const size_t ob_pb   = (size_t)TSEQ * CEMB * 2;     // 196608
    const size_t s_pb    = (size_t)TSEQ * TSEQ * 4;     // 262144 (f32)
    const size_t p_pb    = (size_t)TSEQ * TSEQ * 2;     // 131072 (bf16)
    const size_t linv_pb = (size_t)TSEQ * 4;            // 1024
    const size_t per_batch = xb_pb + qkb_pb + vt_pb + ob_pb + s_pb + p_pb + linv_pb;
    const size_t wq_sz = (size_t)CEMB * QKV_N * 2;      // 884736
    const size_t wp_sz = (size_t)CEMB * CEMB * 2;       // 294912
    const size_t fixed = wq_sz + wp_sz;

    size_t avail = (ws_size > fixed) ? (ws_size - fixed) : 0;
    int chunk = (int)(avail / per_batch);
    if (chunk > Btot) chunk = Btot;
    if (chunk < 1) chunk = 1;
    if (chunk >= 8) chunk -= chunk % 8;

    char* p = (char*)d_ws;
    unsigned short* xb   = (unsigned short*)p;  p += xb_pb * chunk;
    unsigned short* QKb  = (unsigned short*)p;  p += qkb_pb * chunk;
    unsigned short* Vt   = (unsigned short*)p;  p += vt_pb * chunk;
    unsigned short* Ob   = (unsigned short*)p;  p += ob_pb * chunk;
    float*          Sbuf = (float*)p;           p += s_pb * chunk;
    unsigned short* Pbuf = (unsigned short*)p;  p += p_pb * chunk;
    float*          Linv = (float*)p;           p += linv_pb * chunk;
    unsigned short* Wqt  = (unsigned short*)p;  p += wq_sz;
    unsigned short* Wpt  = (unsigned short*)p;

    cast_wt_kernel<<<(CEMB * QKV_N + 255) / 256, 256, 0, stream>>>(
        W_qkv, Wqt, CEMB, QKV_N);
    cast_wt_kernel<<<(CEMB * CEMB + 255) / 256, 256, 0, stream>>>(
        W_proj, Wpt, CEMB, CEMB);

    for (int b0 = 0; b0 < Btot; b0 += chunk) {
        int cb = (chunk < Btot - b0) ? chunk : (Btot - b0);
        int Mc = cb * TSEQ;

        int n8 = Mc * CEMB / 8;
        int gx = (n8 + 255) / 256;
        if (gx > 2048) gx = 2048;
        cast_x_kernel<<<gx, 256, 0, stream>>>(
            x + (size_t)b0 * TSEQ * CEMB, xb, n8);

        // QKV GEMM: q/k -> QKb bf16 ld=768, v -> Vt transposed
        gemm_bf16_kernel<1><<<dim3(QKV_N / 128, Mc / 128), 256, 0, stream>>>(
            xb, Wqt, b_qkv, QKb, Vt, Mc, QKV_N, CEMB);

        // S = QK^T (3 causal tiles per batch, f32)
        qk_gemm_kernel<<<dim3(3, cb), 256, 0, stream>>>(QKb, Sbuf);

        // row softmax -> unnormalized bf16 P + Linv
        softmax_rows_kernel<<<dim3(64, cb), 256, 0, stream>>>(Sbuf, Pbuf, Linv);

        // O = P·V (causal-truncated K), x Linv in epilogue -> Ob bf16
        pv_gemm_kernel<<<dim3(6, cb), 256, 0, stream>>>(Pbuf, Vt, Linv, Ob);

        // proj GEMM (fp32 out)
        gemm_bf16_kernel<0><<<dim3(CEMB / 128, Mc / 128), 256, 0, stream>>>(
            Ob, Wpt, b_proj, out + (size_t)b0 * TSEQ * CEMB, nullptr, Mc, CEMB, CEMB);
    }
}